// Round 11
// baseline (382.730 us; speedup 1.0000x reference)
//
#include <hip/hip_runtime.h>

#define N_NODES 100000
#define N_EDGES 1600000
#define D 128
#define TILE_ROWS 32
#define N_TILES (N_NODES / TILE_ROWS)        // 3125
#define GEMM_BLOCKS 512
#define CHUNK 8192
#define NC ((N_EDGES + CHUNK - 1) / CHUNK)   // 196 chunks
#define NB ((N_NODES + 255) / 256)           // 391 buckets (256 nodes each)
#define HLEN (NB * NC)                       // 76636
#define SCAN_BLK ((HLEN + 1023) / 1024)      // 75
#define SB_SHIFT 13
#define NSB 13
#define SBP 17
#define EBUF 5120                            // LDS staging (u64); mean bucket = 4096

typedef unsigned int uint;
typedef unsigned long long u64;
typedef short short8 __attribute__((ext_vector_type(8)));
typedef float f32x4 __attribute__((ext_vector_type(4)));

__device__ inline ushort f2bf(float f) {  // RTNE bf16 (finite inputs)
    union { float f; uint u; } v; v.f = f;
    uint r = v.u + 0x7fffu + ((v.u >> 16) & 1u);
    return (ushort)(r >> 16);
}
__device__ inline float bf2f(ushort b) {
    union { uint u; float f; } v; v.u = ((uint)b) << 16;
    return v.f;
}

// ================= CSR build: two-level bucket sort, no global atomics =================

__global__ __launch_bounds__(256) void k_hist(const int* __restrict__ dst, int* __restrict__ H) {
    __shared__ int hist[NB];
    int c = blockIdx.x;
    for (int i = threadIdx.x; i < NB; i += 256) hist[i] = 0;
    __syncthreads();
    int base = c * CHUNK;
    int lim = N_EDGES - base; if (lim > CHUNK) lim = CHUNK;
    for (int k = threadIdx.x; k < lim; k += 256)
        atomicAdd(&hist[dst[base + k] >> 8], 1);
    __syncthreads();
    for (int i = threadIdx.x; i < NB; i += 256) H[c * NB + i] = hist[i];
}

// exclusive scan of H in bucket-major logical order l = b*NC + c.
__global__ __launch_bounds__(256) void k_scanA(const int* __restrict__ H, int* __restrict__ HOFF,
                                               int* __restrict__ bsum) {
    __shared__ int sd[256];
    int t = threadIdx.x;
    int base = blockIdx.x * 1024 + t * 4;
    int v[4];
#pragma unroll
    for (int j = 0; j < 4; ++j) {
        int l = base + j;
        v[j] = (l < HLEN) ? H[(l % NC) * NB + (l / NC)] : 0;   // transposed read
    }
    int lsum = v[0] + v[1] + v[2] + v[3];
    sd[t] = lsum;
    __syncthreads();
    for (int off = 1; off < 256; off <<= 1) {
        int x = (t >= off) ? sd[t - off] : 0;
        __syncthreads();
        sd[t] += x;
        __syncthreads();
    }
    int excl = sd[t] - lsum;
    if (base + 0 < HLEN) HOFF[base + 0] = excl;
    if (base + 1 < HLEN) HOFF[base + 1] = excl + v[0];
    if (base + 2 < HLEN) HOFF[base + 2] = excl + v[0] + v[1];
    if (base + 3 < HLEN) HOFF[base + 3] = excl + v[0] + v[1] + v[2];
    if (t == 255) bsum[blockIdx.x] = sd[255];
}

// scanC with in-block redundant scan of the 75 block sums (scanB merged away)
__global__ __launch_bounds__(256) void k_scanC(int* __restrict__ HOFF, const int* __restrict__ bsum) {
    __shared__ int sd[256];
    __shared__ int sb[256];
    int t = threadIdx.x;
    int v = (t < SCAN_BLK) ? bsum[t] : 0;
    sd[t] = v;
    __syncthreads();
    for (int off = 1; off < 256; off <<= 1) {
        int x = (t >= off) ? sd[t - off] : 0;
        __syncthreads();
        sd[t] += x;
        __syncthreads();
    }
    sb[t] = sd[t] - v;   // exclusive prefix of block sums
    __syncthreads();
    int i = blockIdx.x * 256 + t;
    if (i < HLEN) HOFF[i] += sb[i >> 10];
}

// scatter u64 records (src | dst<<17 | Q30(ew)<<34) into bucket-major tmp.
__global__ __launch_bounds__(256) void k_pscat(const int* __restrict__ src, const int* __restrict__ dst,
                                               const float* __restrict__ ew, const int* __restrict__ HOFF,
                                               u64* __restrict__ tmp) {
    __shared__ int cur[NB];
    int c = blockIdx.x;
    for (int i = threadIdx.x; i < NB; i += 256) cur[i] = HOFF[i * NC + c];
    __syncthreads();
    int base = c * CHUNK;
    int lim = N_EDGES - base; if (lim > CHUNK) lim = CHUNK;
    for (int k = threadIdx.x; k < lim; k += 256) {
        int e = base + k;
        int s = src[e], t = dst[e];
        u64 q = (u64)llrintf(ew[e] * 1073741824.0f);   // Q30, ew in [0,1)
        int pos = atomicAdd(&cur[t >> 8], 1);
        tmp[pos] = (u64)s | ((u64)t << 17) | (q << 34);
    }
}

// Fused bucket kernel (race-free: edges carry cf = w*dis[dst] only).
__global__ __launch_bounds__(256) void k_bfused(const int* __restrict__ HOFF, const u64* __restrict__ tmp,
                                                float* __restrict__ dis, int* __restrict__ rowptr,
                                                int2* __restrict__ edges) {
    __shared__ u64 ebuf[EBUF];        // 40 KB
    __shared__ u64 degq[256];
    __shared__ int cnt2[256][SBP];
    __shared__ int sd[256];
    __shared__ float disl[256];
    int b = blockIdx.x, t = threadIdx.x;
    int beg = HOFF[b * NC];
    int end = (b + 1 < NB) ? HOFF[(b + 1) * NC] : N_EDGES;
    int total = end - beg;
    bool fit = (total <= EBUF);
    degq[t] = 0;
#pragma unroll
    for (int j = 0; j < SBP; ++j) cnt2[t][j] = 0;
    __syncthreads();
    int lo = b << 8;

    for (int e = beg + t; e < end; e += 256) {
        u64 r = tmp[e];
        if (fit) ebuf[e - beg] = r;
        int loc = (int)((r >> 17) & 0x1FFFF) - lo;
        int sb = (int)(r & 0x1FFFF) >> SB_SHIFT;
        atomicAdd(&cnt2[loc][sb], 1);
        atomicAdd(&degq[loc], r >> 34);
    }
    __syncthreads();

    int n = lo + t;
    float dv = 0.0f;
    if (n < N_NODES) {
        float deg = (float)((double)degq[t] * (1.0 / 1073741824.0));
        dv = rsqrtf(deg + 1.0f);   // self-loop weight 1
        dis[n] = dv;
    }
    disl[t] = dv;
    int tot = 0;
#pragma unroll
    for (int j = 0; j < NSB; ++j) tot += cnt2[t][j];
    sd[t] = tot;
    __syncthreads();
    for (int off = 1; off < 256; off <<= 1) {
        int x = (t >= off) ? sd[t - off] : 0;
        __syncthreads();
        sd[t] += x;
        __syncthreads();
    }
    int nbase = beg + sd[t] - tot;
    if (n < N_NODES) rowptr[n] = nbase;
    if (b == NB - 1 && t == 0) rowptr[N_NODES] = N_EDGES;
    {
        int run = nbase;
#pragma unroll
        for (int j = 0; j < NSB; ++j) { int c = cnt2[t][j]; cnt2[t][j] = run; run += c; }
    }
    __syncthreads();

    if (fit) {
        for (int i = t; i < total; i += 256) {
            u64 r = ebuf[i];
            int s = (int)(r & 0x1FFFF);
            int loc = (int)((r >> 17) & 0x1FFFF) - lo;
            float w = (float)(r >> 34) * (1.0f / 1073741824.0f);
            float cf = w * disl[loc];
            int pos = atomicAdd(&cnt2[loc][s >> SB_SHIFT], 1);
            edges[pos] = make_int2(s, __float_as_int(cf));
        }
    } else {
        for (int e = beg + t; e < end; e += 256) {
            u64 r = tmp[e];
            int s = (int)(r & 0x1FFFF);
            int loc = (int)((r >> 17) & 0x1FFFF) - lo;
            float w = (float)(r >> 34) * (1.0f / 1073741824.0f);
            float cf = w * disl[loc];
            int pos = atomicAdd(&cnt2[loc][s >> SB_SHIFT], 1);
            edges[pos] = make_int2(s, __float_as_int(cf));
        }
    }
}

// ---------------- W split (all 3 layers in one launch) ----------------
__global__ void k_wsplit3(const float* __restrict__ W1, const float* __restrict__ W2,
                          const float* __restrict__ W3, ushort* __restrict__ wsp) {
    int gid = blockIdx.x * 256 + threadIdx.x;   // 0..49151
    int l = gid >> 14;
    int i = gid & 16383;
    const float* W = (l == 0) ? W1 : (l == 1) ? W2 : W3;
    ushort* Wht = wsp + l * 32768;
    ushort* Wlt = Wht + 16384;
    int k = i >> 7, c = i & 127;
    float w = W[i];
    ushort wh = f2bf(w);
    ushort wl = f2bf(w - bf2f(wh));
    int j = k >> 3;
    int off = c * 128 + (((j ^ (c & 7)) << 3) | (k & 7));
    Wht[off] = wh;
    Wlt[off] = wl;
}

// ---------------- shared MFMA core (macro-free via inline fn) ----------------
__device__ inline void gemm_core(const ushort* WH, const ushort* WL,
                                 const ushort* XH, const ushort* XL,
                                 int lr, int g, int c0, int c1, f32x4 acc[2][2]) {
#pragma unroll
    for (int ks = 0; ks < 4; ++ks) {
        int co = ((ks * 4 + g) ^ (lr & 7)) << 3;
        short8 ah0 = *(short8*)&XH[lr * 128 + co];
        short8 ah1 = *(short8*)&XH[(16 + lr) * 128 + co];
        short8 al0 = *(short8*)&XL[lr * 128 + co];
        short8 al1 = *(short8*)&XL[(16 + lr) * 128 + co];
        short8 bh0 = *(short8*)&WH[c0 * 128 + co];
        short8 bh1 = *(short8*)&WH[c1 * 128 + co];
        short8 bl0 = *(short8*)&WL[c0 * 128 + co];
        short8 bl1 = *(short8*)&WL[c1 * 128 + co];

        acc[0][0] = __builtin_amdgcn_mfma_f32_16x16x32_bf16(ah0, bh0, acc[0][0], 0, 0, 0);
        acc[0][1] = __builtin_amdgcn_mfma_f32_16x16x32_bf16(ah0, bh1, acc[0][1], 0, 0, 0);
        acc[1][0] = __builtin_amdgcn_mfma_f32_16x16x32_bf16(ah1, bh0, acc[1][0], 0, 0, 0);
        acc[1][1] = __builtin_amdgcn_mfma_f32_16x16x32_bf16(ah1, bh1, acc[1][1], 0, 0, 0);
        acc[0][0] = __builtin_amdgcn_mfma_f32_16x16x32_bf16(al0, bh0, acc[0][0], 0, 0, 0);
        acc[0][1] = __builtin_amdgcn_mfma_f32_16x16x32_bf16(al0, bh1, acc[0][1], 0, 0, 0);
        acc[1][0] = __builtin_amdgcn_mfma_f32_16x16x32_bf16(al1, bh0, acc[1][0], 0, 0, 0);
        acc[1][1] = __builtin_amdgcn_mfma_f32_16x16x32_bf16(al1, bh1, acc[1][1], 0, 0, 0);
        acc[0][0] = __builtin_amdgcn_mfma_f32_16x16x32_bf16(ah0, bl0, acc[0][0], 0, 0, 0);
        acc[0][1] = __builtin_amdgcn_mfma_f32_16x16x32_bf16(ah0, bl1, acc[0][1], 0, 0, 0);
        acc[1][0] = __builtin_amdgcn_mfma_f32_16x16x32_bf16(ah1, bl0, acc[1][0], 0, 0, 0);
        acc[1][1] = __builtin_amdgcn_mfma_f32_16x16x32_bf16(ah1, bl1, acc[1][1], 0, 0, 0);
    }
}

// ---------------- GEMM (layer 1): fp32 x -> split in-kernel ----------------
__global__ __launch_bounds__(256) void k_gemm_split(
    const float* __restrict__ x, const ushort* __restrict__ Wht,
    const ushort* __restrict__ Wlt, const float* __restrict__ dis,
    ushort* __restrict__ hb)
{
    __shared__ ushort WH[16384];
    __shared__ ushort WL[16384];
    __shared__ ushort XH[4096];
    __shared__ ushort XL[4096];

    const int tx = threadIdx.x;
    for (int i = tx; i < 2048; i += 256) {
        ((uint4*)WH)[i] = ((const uint4*)Wht)[i];
        ((uint4*)WL)[i] = ((const uint4*)Wlt)[i];
    }

    const int wv = tx >> 6, lane = tx & 63, lr = lane & 15, g = lane >> 4;
    const int c0 = wv * 32 + lr, c1 = c0 + 16;
    const int xr = (tx * 2) >> 4, xjb = (tx * 2) & 15;

    for (int tile = blockIdx.x; tile < N_TILES; tile += GEMM_BLOCKS) {
        const int row0 = tile * TILE_ROWS;
        __syncthreads();
        {
            const float* xp = x + (size_t)(row0 + xr) * D;
#pragma unroll
            for (int c = 0; c < 2; ++c) {
                int j = xjb + c;
                float4 a0 = *(const float4*)(xp + j * 8);
                float4 a1 = *(const float4*)(xp + j * 8 + 4);
                float v[8] = {a0.x, a0.y, a0.z, a0.w, a1.x, a1.y, a1.z, a1.w};
                uint4 uh, ul;
                uint* ph = (uint*)&uh; uint* pl = (uint*)&ul;
#pragma unroll
                for (int e = 0; e < 4; ++e) {
                    ushort h0 = f2bf(v[2 * e]),     h1 = f2bf(v[2 * e + 1]);
                    ushort l0 = f2bf(v[2 * e] - bf2f(h0));
                    ushort l1 = f2bf(v[2 * e + 1] - bf2f(h1));
                    ph[e] = (uint)h0 | ((uint)h1 << 16);
                    pl[e] = (uint)l0 | ((uint)l1 << 16);
                }
                int off = xr * 16 + (j ^ (xr & 7));
                ((uint4*)XH)[off] = uh;
                ((uint4*)XL)[off] = ul;
            }
        }
        __syncthreads();

        f32x4 acc[2][2] = {};
        gemm_core(WH, WL, XH, XL, lr, g, c0, c1, acc);

#pragma unroll
        for (int rt = 0; rt < 2; ++rt) {
            float4 dvq = *(const float4*)&dis[row0 + rt * 16 + g * 4];
            const float dvv[4] = {dvq.x, dvq.y, dvq.z, dvq.w};
#pragma unroll
            for (int ct = 0; ct < 2; ++ct) {
                int colb = wv * 32 + ct * 16 + lr;
#pragma unroll
                for (int e = 0; e < 4; ++e) {
                    int row = row0 + rt * 16 + g * 4 + e;
                    hb[(size_t)row * D + colb] = f2bf(dvv[e] * acc[rt][ct][e]);
                }
            }
        }
    }
}

// ---------------- GEMM (layers 2,3): pre-split XH/XL -> linear stage ----------------
__global__ __launch_bounds__(256) void k_gemm_direct(
    const ushort* __restrict__ xhg, const ushort* __restrict__ xlg,
    const ushort* __restrict__ Wht, const ushort* __restrict__ Wlt,
    const float* __restrict__ dis, ushort* __restrict__ hb)
{
    __shared__ ushort WH[16384];
    __shared__ ushort WL[16384];
    __shared__ ushort XH[4096];
    __shared__ ushort XL[4096];

    const int tx = threadIdx.x;
    for (int i = tx; i < 2048; i += 256) {
        ((uint4*)WH)[i] = ((const uint4*)Wht)[i];
        ((uint4*)WL)[i] = ((const uint4*)Wlt)[i];
    }

    const int wv = tx >> 6, lane = tx & 63, lr = lane & 15, g = lane >> 4;
    const int c0 = wv * 32 + lr, c1 = c0 + 16;

    for (int tile = blockIdx.x; tile < N_TILES; tile += GEMM_BLOCKS) {
        const int row0 = tile * TILE_ROWS;
        __syncthreads();
        {
            const uint4* sh = (const uint4*)xhg + (size_t)tile * 512;
            const uint4* sl = (const uint4*)xlg + (size_t)tile * 512;
#pragma unroll
            for (int i = 0; i < 2; ++i) {
                ((uint4*)XH)[tx + i * 256] = sh[tx + i * 256];
                ((uint4*)XL)[tx + i * 256] = sl[tx + i * 256];
            }
        }
        __syncthreads();

        f32x4 acc[2][2] = {};
        gemm_core(WH, WL, XH, XL, lr, g, c0, c1, acc);

#pragma unroll
        for (int rt = 0; rt < 2; ++rt) {
            float4 dvq = *(const float4*)&dis[row0 + rt * 16 + g * 4];
            const float dvv[4] = {dvq.x, dvq.y, dvq.z, dvq.w};
#pragma unroll
            for (int ct = 0; ct < 2; ++ct) {
                int colb = wv * 32 + ct * 16 + lr;
#pragma unroll
                for (int e = 0; e < 4; ++e) {
                    int row = row0 + rt * 16 + g * 4 + e;
                    hb[(size_t)row * D + colb] = f2bf(dvv[e] * acc[rt][ct][e]);
                }
            }
        }
    }
}

// ---------------- gather ----------------
// emit=1: write pre-split pre-swizzled XH/XL (layers 1,2). emit=0: fp32 out (layer 3).
__global__ __launch_bounds__(256) void k_gather(
    const int* __restrict__ rowptr, const int2* __restrict__ edges,
    const ushort* __restrict__ hb, const float* __restrict__ dis,
    const float* __restrict__ b, const float* __restrict__ alpha,
    ushort* __restrict__ xh, ushort* __restrict__ xl,
    float* __restrict__ outf, int emit)
{
    int gid = blockIdx.x * 256 + threadIdx.x;
    int n = gid >> 6;
    if (n >= N_NODES) return;
    int lane = gid & 63;
    int q = lane >> 4;
    int c0 = (lane & 15) * 8;

    int beg = rowptr[n], end = rowptr[n + 1];
    float acc[8] = {0.f, 0.f, 0.f, 0.f, 0.f, 0.f, 0.f, 0.f};

    int e = beg + q;
    for (; e + 4 < end; e += 8) {
        int2 sc0 = edges[e];
        int2 sc1 = edges[e + 4];
        uint4 hv0 = *(const uint4*)&hb[(size_t)sc0.x * D + c0];
        uint4 hv1 = *(const uint4*)&hb[(size_t)sc1.x * D + c0];
        float ca = __int_as_float(sc0.y);
        float cb = __int_as_float(sc1.y);
#pragma unroll
        for (int j = 0; j < 4; ++j) {
            uint w0 = ((const uint*)&hv0)[j];
            uint w1 = ((const uint*)&hv1)[j];
            acc[2 * j]     = fmaf(ca, __uint_as_float(w0 << 16),         acc[2 * j]);
            acc[2 * j + 1] = fmaf(ca, __uint_as_float(w0 & 0xffff0000u), acc[2 * j + 1]);
            acc[2 * j]     = fmaf(cb, __uint_as_float(w1 << 16),         acc[2 * j]);
            acc[2 * j + 1] = fmaf(cb, __uint_as_float(w1 & 0xffff0000u), acc[2 * j + 1]);
        }
    }
    if (e < end) {
        int2 sc = edges[e];
        float c = __int_as_float(sc.y);
        uint4 hv = *(const uint4*)&hb[(size_t)sc.x * D + c0];
#pragma unroll
        for (int j = 0; j < 4; ++j) {
            uint w = ((const uint*)&hv)[j];
            acc[2 * j]     = fmaf(c, __uint_as_float(w << 16),         acc[2 * j]);
            acc[2 * j + 1] = fmaf(c, __uint_as_float(w & 0xffff0000u), acc[2 * j + 1]);
        }
    }

#pragma unroll
    for (int j = 0; j < 8; ++j) {
        acc[j] += __shfl_xor(acc[j], 16);
        acc[j] += __shfl_xor(acc[j], 32);
    }

    if (q == 0) {
        float di = dis[n];
        uint4 hv = *(const uint4*)&hb[(size_t)n * D + c0];
        float r[8];
#pragma unroll
        for (int j = 0; j < 4; ++j) {
            uint w = ((const uint*)&hv)[j];
            float lo = __uint_as_float(w << 16);
            float hi = __uint_as_float(w & 0xffff0000u);
            r[2 * j]     = acc[2 * j]     + di * lo + b[c0 + 2 * j];
            r[2 * j + 1] = acc[2 * j + 1] + di * hi + b[c0 + 2 * j + 1];
        }
#pragma unroll
        for (int j = 0; j < 8; ++j) {
            float av = alpha[c0 + j];
            r[j] = r[j] >= 0.f ? r[j] : av * r[j];
        }
        if (emit) {
            uint4 uh, ul;
            uint* ph = (uint*)&uh; uint* pl = (uint*)&ul;
#pragma unroll
            for (int m = 0; m < 4; ++m) {
                ushort h0 = f2bf(r[2 * m]),     h1 = f2bf(r[2 * m + 1]);
                ushort l0 = f2bf(r[2 * m] - bf2f(h0));
                ushort l1 = f2bf(r[2 * m + 1] - bf2f(h1));
                ph[m] = (uint)h0 | ((uint)h1 << 16);
                pl[m] = (uint)l0 | ((uint)l1 << 16);
            }
            int rr = n & 31, j = lane & 15, tile = n >> 5;
            int off = tile * 512 + rr * 16 + (j ^ (rr & 7));
            ((uint4*)xh)[off] = uh;
            ((uint4*)xl)[off] = ul;
        } else {
            *(float4*)&outf[(size_t)n * D + c0]     = make_float4(r[0], r[1], r[2], r[3]);
            *(float4*)&outf[(size_t)n * D + c0 + 4] = make_float4(r[4], r[5], r[6], r[7]);
        }
    }
}

// ---------------- launch ----------------

extern "C" void kernel_launch(void* const* d_in, const int* in_sizes, int n_in,
                              void* d_out, int out_size, void* d_ws, size_t ws_size,
                              hipStream_t stream) {
    const float* x   = (const float*)d_in[0];
    const int*   ei  = (const int*)d_in[1];
    const float* ew  = (const float*)d_in[2];
    const float* W1  = (const float*)d_in[3];
    const float* b1  = (const float*)d_in[4];
    const float* a1  = (const float*)d_in[5];
    const float* W2  = (const float*)d_in[6];
    const float* b2  = (const float*)d_in[7];
    const float* a2  = (const float*)d_in[8];
    const float* W3  = (const float*)d_in[9];
    const float* b3  = (const float*)d_in[10];
    const float* a3  = (const float*)d_in[11];

    const int* src = ei;
    const int* dst = ei + N_EDGES;

    float* out = (float*)d_out;
    // layers 1-2 intermediate (pre-split bf16 hi/lo) lives in d_out scratch:
    // XHg = first 25.6 MB, XLg = second 25.6 MB. Layer-3 gather overwrites with fp32 out.
    ushort* xhg = (ushort*)d_out;
    ushort* xlg = xhg + (size_t)N_NODES * D;

    // workspace layout, explicit byte offsets, 16B-aligned (~52.8 MB)
    char* base = (char*)d_ws;
    ushort* hb    = (ushort*)(base);               // 25,600,000 B
    int2*   edges = (int2*)(base + 25600000);      // 12,800,000 B
    u64*    tmp   = (u64*)(base + 38400000);       // 12,800,000 B
    float*  dis   = (float*)(base + 51200000);     //    400,000 B
    int*    H     = (int*)(base + 51600000);       //    306,560 B (HLEN padded)
    int*    HOFF  = (int*)(base + 51906560);       //    306,560 B
    int*    bsum  = (int*)(base + 52213120);       //      1,024 B
    int*    rowptr= (int*)(base + 52214144);       //    400,032 B
    ushort* wsp   = (ushort*)(base + 52614176);    //    196,608 B
    ushort* Wht1 = wsp;             ushort* Wlt1 = wsp + 16384;
    ushort* Wht2 = wsp + 32768;     ushort* Wlt2 = wsp + 32768 + 16384;
    ushort* Wht3 = wsp + 65536;     ushort* Wlt3 = wsp + 65536 + 16384;

    // W splits
    k_wsplit3<<<192, 256, 0, stream>>>(W1, W2, W3, wsp);

    // CSR build
    k_hist<<<NC, 256, 0, stream>>>(dst, H);
    k_scanA<<<SCAN_BLK, 256, 0, stream>>>(H, HOFF, bsum);
    k_scanC<<<(HLEN + 255) / 256, 256, 0, stream>>>(HOFF, bsum);
    k_pscat<<<NC, 256, 0, stream>>>(src, dst, ew, HOFF, tmp);
    k_bfused<<<NB, 256, 0, stream>>>(HOFF, tmp, dis, rowptr, edges);

    const int gather_blocks = (N_NODES * 64) / 256;  // 25000

    // ----- layer 1 -----
    k_gemm_split<<<GEMM_BLOCKS, 256, 0, stream>>>(x, Wht1, Wlt1, dis, hb);
    k_gather<<<gather_blocks, 256, 0, stream>>>(rowptr, edges, hb, dis, b1, a1, xhg, xlg, out, 1);
    // ----- layer 2 -----
    k_gemm_direct<<<GEMM_BLOCKS, 256, 0, stream>>>(xhg, xlg, Wht2, Wlt2, dis, hb);
    k_gather<<<gather_blocks, 256, 0, stream>>>(rowptr, edges, hb, dis, b2, a2, xhg, xlg, out, 1);
    // ----- layer 3 -----
    k_gemm_direct<<<GEMM_BLOCKS, 256, 0, stream>>>(xhg, xlg, Wht3, Wlt3, dis, hb);
    k_gather<<<gather_blocks, 256, 0, stream>>>(rowptr, edges, hb, dis, b3, a3, xhg, xlg, out, 0);
}